// Round 6
// baseline (231.491 us; speedup 1.0000x reference)
//
#include <hip/hip_runtime.h>
#include <hip/hip_bf16.h>

// corr: (B=32, C=1024, HW=1024) fp32; select_indices: arange(K=256)
// out:  (B, 2+K, 1024) fp32  [ch0=max over C, ch1=mean over C, ch2..=gathered]

#define BB  32
#define CC  1024
#define HW  1024
#define NCH 16          // channel chunks in pass1 (16 -> half the partial traffic of 32)
#define CPC 64          // channels per chunk

using f32x4 = __attribute__((ext_vector_type(4))) float;

// ---------------------------------------------------------------------------
// Pass 1: one block per (b, chunk). 4 waves; wave w owns channels
// [w*16, w*16+16). Each lane holds 4 float4 spanning all 1024 hw per channel:
// per-channel f64 spatial sum = ONE 6-step shuffle tree per channel.
// Per-hw max/sum partials held in registers, combined once via LDS.
// f64 accumulation for value[] is load-bearing (np ordering at rank-255/256
// boundary) — do not downgrade. Partial stores are nontemporal (read once).
__global__ __launch_bounds__(256)
void k_pass1(const float* __restrict__ corr,
             float* __restrict__ pmax,
             float* __restrict__ psum,
             double* __restrict__ value) {
    __shared__ float4 lmax[4][4][64];   // [wave][k][lane]  16 KB
    __shared__ float4 lsum[4][4][64];   //                  16 KB
    const int tid  = threadIdx.x;
    const int lane = tid & 63;
    const int w    = tid >> 6;          // wave id 0..3
    const int b    = blockIdx.x / NCH;
    const int cc   = blockIdx.x % NCH;

    const float4* cbase = (const float4*)(corr + (((size_t)b * CC) + (size_t)cc * CPC) * HW);

    float4 vmax[4], vsum[4];
    #pragma unroll
    for (int k = 0; k < 4; ++k) {
        vmax[k] = make_float4(-__builtin_inff(), -__builtin_inff(),
                              -__builtin_inff(), -__builtin_inff());
        vsum[k] = make_float4(0.f, 0.f, 0.f, 0.f);
    }

    #pragma unroll 2
    for (int i = 0; i < 16; ++i) {
        const int cl = w * 16 + i;                     // channel within chunk
        const float4* ch = cbase + (size_t)cl * (HW / 4);
        float4 x[4];
        #pragma unroll
        for (int k = 0; k < 4; ++k) x[k] = ch[lane + 64 * k];

        double s = 0.0;
        #pragma unroll
        for (int k = 0; k < 4; ++k) {
            vmax[k].x = fmaxf(vmax[k].x, x[k].x); vmax[k].y = fmaxf(vmax[k].y, x[k].y);
            vmax[k].z = fmaxf(vmax[k].z, x[k].z); vmax[k].w = fmaxf(vmax[k].w, x[k].w);
            vsum[k].x += x[k].x; vsum[k].y += x[k].y;
            vsum[k].z += x[k].z; vsum[k].w += x[k].w;
            s += ((double)x[k].x + (double)x[k].y) + ((double)x[k].z + (double)x[k].w);
        }
        #pragma unroll
        for (int off = 32; off >= 1; off >>= 1)
            s += __shfl_down(s, off);
        if (lane == 0)
            value[(size_t)b * CC + (size_t)cc * CPC + cl] = s;
    }

    #pragma unroll
    for (int k = 0; k < 4; ++k) { lmax[w][k][lane] = vmax[k]; lsum[w][k][lane] = vsum[k]; }
    __syncthreads();

    // thread t combines the 4 waves for float4-index t
    {
        const int k  = tid >> 6, ln = tid & 63;
        float4 m = lmax[0][k][ln], s = lsum[0][k][ln];
        #pragma unroll
        for (int ww = 1; ww < 4; ++ww) {
            float4 a = lmax[ww][k][ln], d = lsum[ww][k][ln];
            m.x = fmaxf(m.x, a.x); m.y = fmaxf(m.y, a.y);
            m.z = fmaxf(m.z, a.z); m.w = fmaxf(m.w, a.w);
            s.x += d.x; s.y += d.y; s.z += d.z; s.w += d.w;
        }
        const size_t o = ((size_t)blockIdx.x * (HW / 4)) + tid;
        __builtin_nontemporal_store(*(const f32x4*)&m, (f32x4*)pmax + o);
        __builtin_nontemporal_store(*(const f32x4*)&s, (f32x4*)psum + o);
    }
}

// ---------------------------------------------------------------------------
// Rank: counting-rank, 4 threads per channel. Block (256 thr) owns 64 channels;
// thread (c_local = tid>>2, jq = tid&3) counts j in its 256-wide quarter,
// combined via two intra-quad shuffles. LDS padded +1 double per 256 so the
// four quarter-bases hit distinct banks.
// rank[c] = #{c' : v'>v or (v'==v and c'<c)} == stable argsort(-value) position.
__global__ __launch_bounds__(256)
void k_rank(const double* __restrict__ value, int* __restrict__ sorted, int K) {
    __shared__ double vs[CC + 4];
    const int b     = blockIdx.x >> 4;
    const int chunk = blockIdx.x & 15;
    const int tid   = threadIdx.x;

    for (int i = tid; i < CC; i += 256)
        vs[i + (i >> 8)] = value[(size_t)b * CC + i];
    __syncthreads();

    const int    c    = chunk * 64 + (tid >> 2);
    const int    jq   = tid & 3;
    const double my   = vs[c + (c >> 8)];
    const int    jb   = jq * 257;          // padded base of this quarter
    const int    j0   = jq * 256;          // logical base
    int r = 0;
    #pragma unroll 8
    for (int j = 0; j < 256; ++j) {
        const double vj = vs[jb + j];
        r += (vj > my) || (vj == my && (j0 + j) < c) ? 1 : 0;
    }
    r += __shfl_down(r, 2);
    r += __shfl_down(r, 1);
    if (jq == 0 && r < K)
        sorted[(size_t)b * CC + r] = c;
}

// ---------------------------------------------------------------------------
// Tail (fused gather + pass2). Blocks [0, BB*K): gather one channel (4 KB,
// nontemporal store — output is never re-read by us). Blocks [BB*K, +128):
// reduce chunk partials -> out channels 0 (max) and 1 (mean).
// Stream order guarantees rank finished before this kernel starts.
__global__ __launch_bounds__(256)
void k_tail(const float* __restrict__ corr,
            const float* __restrict__ pmax,
            const float* __restrict__ psum,
            const int* __restrict__ sorted,
            const int* __restrict__ selidx,
            float* __restrict__ out, int K) {
    const int NG = BB * K;
    if ((int)blockIdx.x < NG) {
        const int b = blockIdx.x / K;
        const int k = blockIdx.x % K;
        int ks = selidx[k];
        ks = min(max(ks, 0), CC - 1);
        int c = sorted[(size_t)b * CC + ks];
        c = min(max(c, 0), CC - 1);       // guard vs poison if ks >= K

        const f32x4* src = (const f32x4*)(corr + (((size_t)b * CC) + c) * HW);
        f32x4*       dst = (f32x4*)(out + (((size_t)b * (2 + 256)) + 2 + k) * HW);
        __builtin_nontemporal_store(src[threadIdx.x], dst + threadIdx.x);
    } else {
        const int gid = (blockIdx.x - NG) * 256 + threadIdx.x;   // 0 .. B*HW-1
        const int b  = gid >> 10;
        const int hw = gid & (HW - 1);
        float m = -__builtin_inff();
        float s = 0.f;
        #pragma unroll 8
        for (int cc = 0; cc < NCH; ++cc) {
            const size_t o = (((size_t)b * NCH + cc) << 10) + hw;
            m = fmaxf(m, pmax[o]);
            s += psum[o];
        }
        const size_t ob = (size_t)b * (2 + 256) * HW;
        out[ob + hw]      = m;
        out[ob + HW + hw] = s * (1.0f / 1024.0f);
    }
}

// ---------------------------------------------------------------------------
extern "C" void kernel_launch(void* const* d_in, const int* in_sizes, int n_in,
                              void* d_out, int out_size, void* d_ws, size_t ws_size,
                              hipStream_t stream) {
    const float* corr = (const float*)d_in[0];
    const int*   sel  = (const int*)d_in[1];
    float*       out  = (float*)d_out;

    const int K = out_size / (BB * HW) - 2;   // 256

    float*  pmax   = (float*)d_ws;                                   // 2 MB
    float*  psum   = pmax + (size_t)BB * NCH * HW;                   // 2 MB
    double* value  = (double*)(psum + (size_t)BB * NCH * HW);        // 256 KB
    int*    sorted = (int*)(value + (size_t)BB * CC);                // 128 KB

    k_pass1<<<BB * NCH, 256, 0, stream>>>(corr, pmax, psum, value);
    k_rank<<<BB * 16, 256, 0, stream>>>(value, sorted, K);
    k_tail<<<BB * K + (BB * HW) / 256, 256, 0, stream>>>(
        corr, pmax, psum, sorted, sel, out, K);
}